// Round 3
// baseline (747.300 us; speedup 1.0000x reference)
//
#include <hip/hip_runtime.h>
#include <stdint.h>

typedef __attribute__((ext_vector_type(8))) short short8;
typedef __attribute__((ext_vector_type(4))) float f32x4;

#define MFMA16(a,b,c) __builtin_amdgcn_mfma_f32_16x16x32_bf16((a),(b),(c),0,0,0)

// async global->LDS DMA, 16B per lane; LDS dest = wave-uniform base + lane*16B
#define GLL16(g, l) __builtin_amdgcn_global_load_lds( \
    (const __attribute__((address_space(1))) void*)(g), \
    (__attribute__((address_space(3))) void*)(l), 16, 0, 0)

__device__ __forceinline__ unsigned short f2bf(float f){
  unsigned u = __builtin_bit_cast(unsigned, f);
  u += 0x7fffu + ((u >> 16) & 1u);
  return (unsigned short)(u >> 16);
}

static constexpr int HW_ = 50176;   // 224*224

// offset of element (row r 0..127, k c64 0..63) inside one 8192-elem panel,
// XOR-swizzled so ds_read_b128 of a 16-lane column slice is conflict-free
__device__ __forceinline__ int panel_off(int r, int c64){
  return r * 64 + ((((c64 >> 3) ^ (r & 7))) << 3) + (c64 & 7);
}

// ---------------- weights fp32 -> bf16 pre-swizzled panels ----------------
// Wqkv panels: mt 0..5 (q:0-1 k:2-3 v:4-5), each [kq 0..3][8192 elems]
__global__ __launch_bounds__(256) void k_convw(const float* __restrict__ Wq, const float* __restrict__ Wk,
                        const float* __restrict__ Wv, const float* __restrict__ Wo,
                        unsigned short* __restrict__ Wqkv, unsigned short* __restrict__ Wob){
  int tg = blockIdx.x * 256 + threadIdx.x;   // grid 128 -> 32768 chunks
  int m = tg >> 13, idx = tg & 8191;
  int o = idx >> 5, ck = idx & 31;           // o 0..255, ck = 8-elem k chunk
  const float* src = (m == 0 ? Wq : m == 1 ? Wk : m == 2 ? Wv : Wo) + o * 256 + ck * 8;
  float4 a = *(const float4*)src, b = *(const float4*)(src + 4);
  short8 v;
  v[0]=f2bf(a.x); v[1]=f2bf(a.y); v[2]=f2bf(a.z); v[3]=f2bf(a.w);
  v[4]=f2bf(b.x); v[5]=f2bf(b.y); v[6]=f2bf(b.z); v[7]=f2bf(b.w);
  int kq = ck >> 3;
  int off = panel_off(o & 127, (ck & 7) * 8);
  if (m < 3) *(short8*)(Wqkv + ((m * 2 + (o >> 7)) * 4 + kq) * 8192 + off) = v;
  else       *(short8*)(Wob  + ((o >> 7) * 4 + kq) * 8192 + off) = v;
}

// ---------------- x (B,C,HW) f32 -> B-panels [b][nt][kq][swz 8192] bf16 ----------------
__global__ __launch_bounds__(256) void k_xpose(const float* __restrict__ x, unsigned short* __restrict__ xbT){
  int bid = blockIdx.x;
  int pt = bid % 784; int rest = bid / 784;
  int ct = rest & 3;  int b = rest >> 2;
  __shared__ unsigned short tile[64 * 72];
  int t = threadIdx.x;
#pragma unroll
  for (int it = 0; it < 4; ++it){
    int idx = it * 256 + t;
    int c = idx >> 4, s = idx & 15;          // c: 0..63 channel, s: 0..15 (4-px group)
    float4 v = *(const float4*)(x + ((size_t)(b * 256 + ct * 64 + c)) * HW_ + pt * 64 + s * 4);
    float vv[4] = {v.x, v.y, v.z, v.w};
#pragma unroll
    for (int j = 0; j < 4; ++j){
      int px = s * 4 + j;
      int g = (px >> 3) & 7;
      tile[px * 72 + (((c >> 3) ^ g) << 3) + (c & 7)] = f2bf(vv[j]);
    }
  }
  __syncthreads();
#pragma unroll
  for (int it = 0; it < 2; ++it){
    int idx = it * 256 + t;
    int p = idx >> 3, s = idx & 7;           // p: 0..63 px, s: 0..7 channel chunk
    int g = (p >> 3) & 7;
    short8 v = *(const short8*)&tile[p * 72 + ((s ^ g) << 3)];
    int pg = pt * 64 + p;                    // global pixel 0..50175
    size_t off = ((size_t)((b * 392 + (pg >> 7)) * 4 + ct)) * 8192 + panel_off(pg & 127, s * 8);
    *(short8*)(xbT + off) = v;
  }
}

// ---------------- GEMM qkv: 128x128 tile, global_load_lds staging from panels ----------------
__global__ __launch_bounds__(256) void k_gemm_qkv(const unsigned short* __restrict__ Wp,
                                                  const unsigned short* __restrict__ Bp,
                                                  unsigned short* __restrict__ qkvT){
  int bid = blockIdx.x;
  int wg = (bid & 7) * 1176 + (bid >> 3);    // XCD-contiguous remap (9408 = 8*1176)
  int mt = wg % 6; int rest = wg / 6;        // mt fastest -> B-panel L2 reuse on-XCD
  int nt = rest % 392; int b = rest / 392;

  __shared__ __align__(16) unsigned short lds[17408];  // A[0..8191] B[8192..16383]; epilogue Ct[128][136]
  unsigned short* Alds = lds;
  unsigned short* Blds = lds + 8192;

  int tid = threadIdx.x;
  int lane = tid & 63;
  int wave = tid >> 6;
  int wm = wave >> 1, wn = wave & 1;

  const unsigned short* Apan = Wp + (size_t)mt * 4 * 8192;
  const unsigned short* Bpan = Bp + ((size_t)(b * 392 + nt)) * 4 * 8192;

  int aoff[2][4], boff[2][4];
#pragma unroll
  for (int kk = 0; kk < 2; ++kk)
#pragma unroll
    for (int i = 0; i < 4; ++i){
      int rowA = wm * 64 + i * 16 + (lane & 15);
      aoff[kk][i] = rowA * 64 + (((kk * 4 + (lane >> 4)) ^ (rowA & 7)) << 3);
      int rowB = wn * 64 + i * 16 + (lane & 15);
      boff[kk][i] = rowB * 64 + (((kk * 4 + (lane >> 4)) ^ (rowB & 7)) << 3);
    }
  int cb = wave * 2048;                      // per-wave staging region (elems)
  f32x4 acc[4][4] = {};

  for (int kq = 0; kq < 4; ++kq){
    __syncthreads();                          // prev tile reads done
#pragma unroll
    for (int j = 0; j < 4; ++j){
      int o2 = cb + j * 512;
      GLL16(Apan + kq * 8192 + o2 + lane * 8, Alds + o2);
      GLL16(Bpan + kq * 8192 + o2 + lane * 8, Blds + o2);
    }
    asm volatile("s_waitcnt vmcnt(0)" ::: "memory");
    __syncthreads();
#pragma unroll
    for (int kk = 0; kk < 2; ++kk){
      short8 af[4], bfv[4];
#pragma unroll
      for (int i = 0; i < 4; ++i) af[i]  = *(const short8*)(Alds + aoff[kk][i]);
#pragma unroll
      for (int j = 0; j < 4; ++j) bfv[j] = *(const short8*)(Blds + boff[kk][j]);
#pragma unroll
      for (int i = 0; i < 4; ++i)
#pragma unroll
        for (int j = 0; j < 4; ++j)
          acc[i][j] = MFMA16(af[i], bfv[j], acc[i][j]);
    }
  }
  __syncthreads();
  // transpose in LDS -> coalesced pixel-major store
#pragma unroll
  for (int i = 0; i < 4; ++i)
#pragma unroll
    for (int j = 0; j < 4; ++j){
      int o_loc = wm * 64 + i * 16 + (lane >> 4) * 4;
      int n_loc = wn * 64 + j * 16 + (lane & 15);
      unsigned long long pk =
          (unsigned long long)f2bf(acc[i][j][0]) |
          ((unsigned long long)f2bf(acc[i][j][1]) << 16) |
          ((unsigned long long)f2bf(acc[i][j][2]) << 32) |
          ((unsigned long long)f2bf(acc[i][j][3]) << 48);
      *(unsigned long long*)(lds + n_loc * 136 + o_loc) = pk;
    }
  __syncthreads();
  size_t outb = (size_t)b * HW_ + (size_t)nt * 128;
  int n_loc = tid >> 1, half = tid & 1;
#pragma unroll
  for (int cc = 0; cc < 8; ++cc){
    short8 v = *(const short8*)(lds + n_loc * 136 + half * 64 + cc * 8);
    *(short8*)(qkvT + (outb + n_loc) * 768 + mt * 128 + half * 64 + cc * 8) = v;
  }
}

// ---------------- window attention, 1 wave = 1 (b,window,head); writes B-panel ----------------
__global__ __launch_bounds__(64) void k_attn(const unsigned short* __restrict__ qkvT,
                                             unsigned short* __restrict__ attnP){
  int bid = blockIdx.x;
  int wg = (bid & 7) * 4096 + (bid >> 3);    // 32768 = 8*4096; heads of a window stay on-XCD
  int h = wg & 7;
  int win = (wg >> 3) & 1023;
  int b = wg >> 13;
  int wh = win >> 5, ww = win & 31;
  int lane = threadIdx.x;

  __shared__ unsigned short sVT[2048];  // [32 d][64 px] pitch 64, XOR swz on d
  __shared__ unsigned short sP[4096];   // [64 q][64 kp] pitch 64, XOR swz on q

  const size_t rowbase = (size_t)b * HW_;
  auto pxaddr = [&](int px){ return rowbase + (size_t)((wh*7 + px/7)*224 + ww*7 + px%7); };

  { // stage V -> V^T in LDS (zero pad cols 49..63)
    int px = lane < 49 ? lane : 48;
    const unsigned short* src = qkvT + pxaddr(px) * 768 + 512 + h * 32;
    short8 v0 = *(const short8*)(src);
    short8 v1 = *(const short8*)(src + 8);
    short8 v2 = *(const short8*)(src + 16);
    short8 v3 = *(const short8*)(src + 24);
    bool val = (lane < 49);
    unsigned short e[32];
#pragma unroll
    for (int d = 0; d < 8; ++d){
      e[d]    = (unsigned short)v0[d];  e[8+d]  = (unsigned short)v1[d];
      e[16+d] = (unsigned short)v2[d];  e[24+d] = (unsigned short)v3[d];
    }
#pragma unroll
    for (int d = 0; d < 32; ++d){
      int bo = (d * 128 + lane * 2) ^ ((d & 7) << 4);
      sVT[bo >> 1] = val ? e[d] : (unsigned short)0;
    }
  }

  // S^T = K * Q^T
  short8 kf[4], qf[4];
#pragma unroll
  for (int i = 0; i < 4; ++i){
    int px = i * 16 + (lane & 15); if (px > 48) px = 48;
    const unsigned short* base = qkvT + pxaddr(px) * 768 + h * 32 + (lane >> 4) * 8;
    qf[i] = *(const short8*)(base);
    kf[i] = *(const short8*)(base + 256);
  }
  f32x4 s[4][4] = {};
#pragma unroll
  for (int mi = 0; mi < 4; ++mi)
#pragma unroll
    for (int ni = 0; ni < 4; ++ni)
      s[mi][ni] = MFMA16(kf[mi], qf[ni], s[mi][ni]);

  const float cexp = 0.25504437f;   // log2(e)/sqrt(32)
#pragma unroll
  for (int ni = 0; ni < 4; ++ni){
    float m = -3.0e38f;
#pragma unroll
    for (int mi = 0; mi < 4; ++mi)
#pragma unroll
      for (int r = 0; r < 4; ++r){
        int kp = mi * 16 + ((lane >> 4) * 4) + r;
        if (kp < 49) m = fmaxf(m, s[mi][ni][r]);
      }
    m = fmaxf(m, __shfl_xor(m, 16));
    m = fmaxf(m, __shfl_xor(m, 32));
    float sum = 0.f;
    float pv[4][4];
#pragma unroll
    for (int mi = 0; mi < 4; ++mi)
#pragma unroll
      for (int r = 0; r < 4; ++r){
        int kp = mi * 16 + ((lane >> 4) * 4) + r;
        float e2 = (kp < 49) ? exp2f((s[mi][ni][r] - m) * cexp) : 0.f;
        pv[mi][r] = e2; sum += e2;
      }
    sum += __shfl_xor(sum, 16);
    sum += __shfl_xor(sum, 32);
    float inv = 1.0f / sum;
    int q = ni * 16 + (lane & 15);
#pragma unroll
    for (int mi = 0; mi < 4; ++mi)
#pragma unroll
      for (int r = 0; r < 4; ++r){
        int kp = mi * 16 + ((lane >> 4) * 4) + r;
        int bo = (q * 128 + kp * 2) ^ ((q & 7) << 4);
        sP[bo >> 1] = f2bf(pv[mi][r] * inv);
      }
  }

  // O = P * V
  f32x4 o[4][2] = {};
#pragma unroll
  for (int kc = 0; kc < 2; ++kc){
    short8 pa[4], vb[2];
#pragma unroll
    for (int mtp = 0; mtp < 4; ++mtp){
      int row = mtp * 16 + (lane & 15);
      int bo = (row * 128 + kc * 64 + (lane >> 4) * 16) ^ ((row & 7) << 4);
      pa[mtp] = *(const short8*)(sP + (bo >> 1));
    }
#pragma unroll
    for (int ntp = 0; ntp < 2; ++ntp){
      int row = ntp * 16 + (lane & 15);
      int bo = (row * 128 + kc * 64 + (lane >> 4) * 16) ^ ((row & 7) << 4);
      vb[ntp] = *(const short8*)(sVT + (bo >> 1));
    }
#pragma unroll
    for (int mtp = 0; mtp < 4; ++mtp)
#pragma unroll
      for (int ntp = 0; ntp < 2; ++ntp)
        o[mtp][ntp] = MFMA16(pa[mtp], vb[ntp], o[mtp][ntp]);
  }

  // store into pre-swizzled B-panel for the out-GEMM
#pragma unroll
  for (int mtp = 0; mtp < 4; ++mtp)
#pragma unroll
    for (int r = 0; r < 4; ++r){
      int q = mtp * 16 + (lane >> 4) * 4 + r;
      if (q < 49){
        int pg = (wh * 7 + q / 7) * 224 + ww * 7 + q % 7;  // global pixel
        int nt = pg >> 7, pr = pg & 127;
        size_t pbase = ((size_t)(b * 392 + nt)) * 4 * 8192;
#pragma unroll
        for (int ntp = 0; ntp < 2; ++ntp){
          int c = h * 32 + ntp * 16 + (lane & 15);
          attnP[pbase + (size_t)(c >> 6) * 8192 + panel_off(pr, c & 63)] = f2bf(o[mtp][ntp][r]);
        }
      }
    }
}

// ---------------- GEMM out + residual + BN partial stats ----------------
__global__ __launch_bounds__(256) void k_gemm_out(const unsigned short* __restrict__ Wp,
                                                  const unsigned short* __restrict__ Bp,
                                                  const float* __restrict__ x,
                                                  float* __restrict__ y,
                                                  float* __restrict__ stats){
  int bid = blockIdx.x;
  int wg = (bid & 7) * 392 + (bid >> 3);     // 3136 = 8*392
  int mt = wg & 1; int rest = wg >> 1;       // mt fastest
  int nt = rest % 392; int b = rest / 392;

  __shared__ __align__(16) unsigned short lds[16384];
  unsigned short* Alds = lds;
  unsigned short* Blds = lds + 8192;

  int tid = threadIdx.x;
  int lane = tid & 63;
  int wave = tid >> 6;
  int wm = wave >> 1, wn = wave & 1;

  const unsigned short* Apan = Wp + (size_t)mt * 4 * 8192;
  const unsigned short* Bpan = Bp + ((size_t)(b * 392 + nt)) * 4 * 8192;

  int aoff[2][4], boff[2][4];
#pragma unroll
  for (int kk = 0; kk < 2; ++kk)
#pragma unroll
    for (int i = 0; i < 4; ++i){
      int rowA = wm * 64 + i * 16 + (lane & 15);
      aoff[kk][i] = rowA * 64 + (((kk * 4 + (lane >> 4)) ^ (rowA & 7)) << 3);
      int rowB = wn * 64 + i * 16 + (lane & 15);
      boff[kk][i] = rowB * 64 + (((kk * 4 + (lane >> 4)) ^ (rowB & 7)) << 3);
    }
  int cb = wave * 2048;
  f32x4 acc[4][4] = {};

  for (int kq = 0; kq < 4; ++kq){
    __syncthreads();
#pragma unroll
    for (int j = 0; j < 4; ++j){
      int o2 = cb + j * 512;
      GLL16(Apan + kq * 8192 + o2 + lane * 8, Alds + o2);
      GLL16(Bpan + kq * 8192 + o2 + lane * 8, Blds + o2);
    }
    asm volatile("s_waitcnt vmcnt(0)" ::: "memory");
    __syncthreads();
#pragma unroll
    for (int kk = 0; kk < 2; ++kk){
      short8 af[4], bfv[4];
#pragma unroll
      for (int i = 0; i < 4; ++i) af[i]  = *(const short8*)(Alds + aoff[kk][i]);
#pragma unroll
      for (int j = 0; j < 4; ++j) bfv[j] = *(const short8*)(Blds + boff[kk][j]);
#pragma unroll
      for (int i = 0; i < 4; ++i)
#pragma unroll
        for (int j = 0; j < 4; ++j)
          acc[i][j] = MFMA16(af[i], bfv[j], acc[i][j]);
    }
  }
  // epilogue: residual add, fp32 store, per-channel partial sums
  float ps[4][4] = {}, pq[4][4] = {};
#pragma unroll
  for (int i = 0; i < 4; ++i)
#pragma unroll
    for (int j = 0; j < 4; ++j){
      int o = mt * 128 + wm * 64 + i * 16 + (lane >> 4) * 4;
      int p = nt * 128 + wn * 64 + j * 16 + (lane & 15);
      size_t base = ((size_t)(b * 256 + o)) * HW_ + p;
#pragma unroll
      for (int r2 = 0; r2 < 4; ++r2){
        float v = acc[i][j][r2] + x[base + (size_t)r2 * HW_];
        y[base + (size_t)r2 * HW_] = v;
        ps[i][r2] += v;
        pq[i][r2] += v * v;
      }
    }
#pragma unroll
  for (int i = 0; i < 4; ++i)
#pragma unroll
    for (int r2 = 0; r2 < 4; ++r2){
      float a = ps[i][r2], q2 = pq[i][r2];
      a += __shfl_xor(a, 1);  q2 += __shfl_xor(q2, 1);
      a += __shfl_xor(a, 2);  q2 += __shfl_xor(q2, 2);
      a += __shfl_xor(a, 4);  q2 += __shfl_xor(q2, 4);
      a += __shfl_xor(a, 8);  q2 += __shfl_xor(q2, 8);
      if ((lane & 15) == 0){
        int o = mt * 128 + wm * 64 + i * 16 + (lane >> 4) * 4 + r2;
        atomicAdd(stats + o, a);
        atomicAdd(stats + 256 + o, q2);
      }
    }
}

// ---------------- in-place normalize (finalizes stats inline) ----------------
__global__ __launch_bounds__(256) void k_norm(float* __restrict__ y, const float* __restrict__ stats,
                                              const float* __restrict__ gamma, const float* __restrict__ beta){
  const long long total = 12845056LL;  // 51380224 / 4
  for (long long idx = (long long)blockIdx.x * 256 + threadIdx.x; idx < total; idx += (long long)gridDim.x * 256){
    int c = (int)((idx / 12544) & 255);
    float mean = stats[c] * (1.f / 200704.f);
    float ex2  = stats[256 + c] * (1.f / 200704.f);
    float rs = rsqrtf(ex2 - mean * mean + 1e-5f);
    float sc = rs * gamma[c];
    float sh = beta[c] - mean * sc;
    float4* p = (float4*)y + idx;
    float4 v = *p;
    v.x = v.x * sc + sh; v.y = v.y * sc + sh; v.z = v.z * sc + sh; v.w = v.w * sc + sh;
    *p = v;
  }
}

extern "C" void kernel_launch(void* const* d_in, const int* in_sizes, int n_in,
                              void* d_out, int out_size, void* d_ws, size_t ws_size,
                              hipStream_t stream){
  const float* x     = (const float*)d_in[0];
  const float* Wq    = (const float*)d_in[1];
  const float* Wk    = (const float*)d_in[2];
  const float* Wv    = (const float*)d_in[3];
  const float* Wo    = (const float*)d_in[4];
  const float* gamma = (const float*)d_in[5];
  const float* beta  = (const float*)d_in[6];
  float* out = (float*)d_out;

  char* ws = (char*)d_ws;
  unsigned short* Wqkv_b = (unsigned short*)ws;                               // 393216 B
  unsigned short* Wo_b   = (unsigned short*)(ws + 393216);                    // 131072 B
  float*          stats  = (float*)(ws + 524288);                             // 2048 B
  unsigned short* xbT    = (unsigned short*)(ws + 1048576);                   // 102760448 B (B-panels)
  unsigned short* qkvT   = (unsigned short*)(ws + 1048576 + 102760448);       // 308281344 B
  unsigned short* attnP  = xbT;  // alias: xbT dead after k_gemm_qkv (stream-ordered)

  hipMemsetAsync(stats, 0, 2048, stream);
  k_convw<<<128, 256, 0, stream>>>(Wq, Wk, Wv, Wo, Wqkv_b, Wo_b);
  k_xpose<<<4 * 4 * 784, 256, 0, stream>>>(x, xbT);
  k_gemm_qkv<<<9408, 256, 0, stream>>>(Wqkv_b, xbT, qkvT);
  k_attn<<<32768, 64, 0, stream>>>(qkvT, attnP);
  k_gemm_out<<<3136, 256, 0, stream>>>(Wo_b, attnP, x, out, stats);
  k_norm<<<4096, 256, 0, stream>>>(out, stats, gamma, beta);
}

// Round 4
// 550.938 us; speedup vs baseline: 1.3564x; 1.3564x over previous
//
#include <hip/hip_runtime.h>
#include <stdint.h>

typedef __attribute__((ext_vector_type(8))) short short8;
typedef __attribute__((ext_vector_type(4))) float f32x4;

#define MFMA16(a,b,c) __builtin_amdgcn_mfma_f32_16x16x32_bf16((a),(b),(c),0,0,0)

// async global->LDS DMA, 16B per lane; LDS dest = wave-uniform base + lane*16B
#define GLL16(g, l) __builtin_amdgcn_global_load_lds( \
    (const __attribute__((address_space(1))) void*)(g), \
    (__attribute__((address_space(3))) void*)(l), 16, 0, 0)

__device__ __forceinline__ unsigned short f2bf(float f){
  unsigned u = __builtin_bit_cast(unsigned, f);
  u += 0x7fffu + ((u >> 16) & 1u);
  return (unsigned short)(u >> 16);
}

static constexpr int HW_ = 50176;   // 224*224

// offset of element (row r 0..127, k c64 0..63) inside one 8192-elem panel,
// XOR-swizzled so ds_read_b128 of a 16-lane column slice is conflict-free
__device__ __forceinline__ int panel_off(int r, int c64){
  return r * 64 + ((((c64 >> 3) ^ (r & 7))) << 3) + (c64 & 7);
}

// ---------------- weights fp32 -> bf16 pre-swizzled panels ----------------
__global__ __launch_bounds__(256) void k_convw(const float* __restrict__ Wq, const float* __restrict__ Wk,
                        const float* __restrict__ Wv, const float* __restrict__ Wo,
                        unsigned short* __restrict__ Wqkv, unsigned short* __restrict__ Wob){
  int tg = blockIdx.x * 256 + threadIdx.x;   // grid 128 -> 32768 chunks
  int m = tg >> 13, idx = tg & 8191;
  int o = idx >> 5, ck = idx & 31;           // o 0..255, ck = 8-elem k chunk
  const float* src = (m == 0 ? Wq : m == 1 ? Wk : m == 2 ? Wv : Wo) + o * 256 + ck * 8;
  float4 a = *(const float4*)src, b = *(const float4*)(src + 4);
  short8 v;
  v[0]=f2bf(a.x); v[1]=f2bf(a.y); v[2]=f2bf(a.z); v[3]=f2bf(a.w);
  v[4]=f2bf(b.x); v[5]=f2bf(b.y); v[6]=f2bf(b.z); v[7]=f2bf(b.w);
  int kq = ck >> 3;
  int off = panel_off(o & 127, (ck & 7) * 8);
  if (m < 3) *(short8*)(Wqkv + ((m * 2 + (o >> 7)) * 4 + kq) * 8192 + off) = v;
  else       *(short8*)(Wob  + ((o >> 7) * 4 + kq) * 8192 + off) = v;
}

// ---------------- x (B,C,HW) f32 -> B-panels [b][nt][kq][swz 8192] bf16 ----------------
__global__ __launch_bounds__(256) void k_xpose(const float* __restrict__ x, unsigned short* __restrict__ xbT){
  int bid = blockIdx.x;
  int pt = bid % 784; int rest = bid / 784;
  int ct = rest & 3;  int b = rest >> 2;
  __shared__ unsigned short tile[64 * 72];
  int t = threadIdx.x;
#pragma unroll
  for (int it = 0; it < 4; ++it){
    int idx = it * 256 + t;
    int c = idx >> 4, s = idx & 15;
    float4 v = *(const float4*)(x + ((size_t)(b * 256 + ct * 64 + c)) * HW_ + pt * 64 + s * 4);
    float vv[4] = {v.x, v.y, v.z, v.w};
#pragma unroll
    for (int j = 0; j < 4; ++j){
      int px = s * 4 + j;
      int g = (px >> 3) & 7;
      tile[px * 72 + (((c >> 3) ^ g) << 3) + (c & 7)] = f2bf(vv[j]);
    }
  }
  __syncthreads();
#pragma unroll
  for (int it = 0; it < 2; ++it){
    int idx = it * 256 + t;
    int p = idx >> 3, s = idx & 7;
    int g = (p >> 3) & 7;
    short8 v = *(const short8*)&tile[p * 72 + ((s ^ g) << 3)];
    int pg = pt * 64 + p;
    size_t off = ((size_t)((b * 392 + (pg >> 7)) * 4 + ct)) * 8192 + panel_off(pg & 127, s * 8);
    *(short8*)(xbT + off) = v;
  }
}

// ---------------- GEMM qkv: 128x128 tile, dbuf GLL16 2-phase prefetch ----------------
__global__ __launch_bounds__(256) void k_gemm_qkv(const unsigned short* __restrict__ Wp,
                                                  const unsigned short* __restrict__ Bp,
                                                  unsigned short* __restrict__ qkvT){
  int bid = blockIdx.x;
  int wg = (bid & 7) * 1176 + (bid >> 3);    // XCD-contiguous remap (9408 = 8*1176)
  int mt = wg % 6; int rest = wg / 6;        // mt fastest -> B-panel L2 reuse on-XCD
  int nt = rest % 392; int b = rest / 392;

  __shared__ __align__(16) unsigned short lds[32768];  // dbuf: [buf][A 8192 | B 8192]

  int tid = threadIdx.x;
  int lane = tid & 63;
  int wave = tid >> 6;
  int wm = wave >> 1, wn = wave & 1;

  const unsigned short* Apan = Wp + (size_t)mt * 4 * 8192;
  const unsigned short* Bpan = Bp + ((size_t)(b * 392 + nt)) * 4 * 8192;

  int aoff[2][4], boff[2][4];
#pragma unroll
  for (int kk = 0; kk < 2; ++kk)
#pragma unroll
    for (int i = 0; i < 4; ++i){
      int rowA = wm * 64 + i * 16 + (lane & 15);
      aoff[kk][i] = rowA * 64 + (((kk * 4 + (lane >> 4)) ^ (rowA & 7)) << 3);
      int rowB = wn * 64 + i * 16 + (lane & 15);
      boff[kk][i] = rowB * 64 + (((kk * 4 + (lane >> 4)) ^ (rowB & 7)) << 3);
    }
  int cb = wave * 2048;                      // per-wave staging quadrant (elems)
  f32x4 acc[4][4] = {};

  // prologue: stage tile 0 into buf 0
#pragma unroll
  for (int j = 0; j < 4; ++j){
    int o2 = cb + j * 512;
    GLL16(Apan + o2 + lane * 8, lds + o2);
    GLL16(Bpan + o2 + lane * 8, lds + 8192 + o2);
  }
  __syncthreads();                           // implicit vmcnt(0): tile 0 landed

  int cur = 0;
  for (int kq = 0; kq < 4; ++kq){
    if (kq < 3){                             // prefetch tile kq+1 into other buf
      const unsigned short* Ak = Apan + (kq + 1) * 8192;
      const unsigned short* Bk = Bpan + (kq + 1) * 8192;
      unsigned short* dst = lds + (cur ^ 1) * 16384;
#pragma unroll
      for (int j = 0; j < 4; ++j){
        int o2 = cb + j * 512;
        GLL16(Ak + o2 + lane * 8, dst + o2);
        GLL16(Bk + o2 + lane * 8, dst + 8192 + o2);
      }
    }
    const unsigned short* Alds = lds + cur * 16384;
    const unsigned short* Blds = Alds + 8192;
#pragma unroll
    for (int kk = 0; kk < 2; ++kk){
      short8 af[4], bfv[4];
#pragma unroll
      for (int i = 0; i < 4; ++i) af[i]  = *(const short8*)(Alds + aoff[kk][i]);
#pragma unroll
      for (int j = 0; j < 4; ++j) bfv[j] = *(const short8*)(Blds + boff[kk][j]);
#pragma unroll
      for (int i = 0; i < 4; ++i)
#pragma unroll
        for (int j = 0; j < 4; ++j)
          acc[i][j] = MFMA16(af[i], bfv[j], acc[i][j]);
    }
    __syncthreads();                         // drains vmcnt(0): tile kq+1 landed; buf swap safe
    cur ^= 1;
  }
  // transpose in LDS -> coalesced pixel-major store (reuse staging LDS)
#pragma unroll
  for (int i = 0; i < 4; ++i)
#pragma unroll
    for (int j = 0; j < 4; ++j){
      int o_loc = wm * 64 + i * 16 + (lane >> 4) * 4;
      int n_loc = wn * 64 + j * 16 + (lane & 15);
      unsigned long long pk =
          (unsigned long long)f2bf(acc[i][j][0]) |
          ((unsigned long long)f2bf(acc[i][j][1]) << 16) |
          ((unsigned long long)f2bf(acc[i][j][2]) << 32) |
          ((unsigned long long)f2bf(acc[i][j][3]) << 48);
      *(unsigned long long*)(lds + n_loc * 136 + o_loc) = pk;
    }
  __syncthreads();
  size_t outb = (size_t)b * HW_ + (size_t)nt * 128;
  int n_loc = tid >> 1, half = tid & 1;
#pragma unroll
  for (int cc = 0; cc < 8; ++cc){
    short8 v = *(const short8*)(lds + n_loc * 136 + half * 64 + cc * 8);
    *(short8*)(qkvT + (outb + n_loc) * 768 + mt * 128 + half * 64 + cc * 8) = v;
  }
}

// ---------------- window attention, 1 wave = 1 (b,window,head); writes B-panel ----------------
__global__ __launch_bounds__(64) void k_attn(const unsigned short* __restrict__ qkvT,
                                             unsigned short* __restrict__ attnP){
  int bid = blockIdx.x;
  int wg = (bid & 7) * 4096 + (bid >> 3);    // 32768 = 8*4096
  int h = wg & 7;
  int win = (wg >> 3) & 1023;
  int b = wg >> 13;
  int wh = win >> 5, ww = win & 31;
  int lane = threadIdx.x;

  __shared__ unsigned short sVT[2048];  // [32 d][64 px] pitch 64, XOR swz on d
  __shared__ unsigned short sP[4096];   // [64 q][64 kp] pitch 64, XOR swz on q; later reused as sO[64][32]

  const size_t rowbase = (size_t)b * HW_;
  auto pxaddr = [&](int px){ return rowbase + (size_t)((wh*7 + px/7)*224 + ww*7 + px%7); };

  { // stage V -> V^T in LDS (zero pad cols 49..63)
    int px = lane < 49 ? lane : 48;
    const unsigned short* src = qkvT + pxaddr(px) * 768 + 512 + h * 32;
    short8 v0 = *(const short8*)(src);
    short8 v1 = *(const short8*)(src + 8);
    short8 v2 = *(const short8*)(src + 16);
    short8 v3 = *(const short8*)(src + 24);
    bool val = (lane < 49);
    unsigned short e[32];
#pragma unroll
    for (int d = 0; d < 8; ++d){
      e[d]    = (unsigned short)v0[d];  e[8+d]  = (unsigned short)v1[d];
      e[16+d] = (unsigned short)v2[d];  e[24+d] = (unsigned short)v3[d];
    }
#pragma unroll
    for (int d = 0; d < 32; ++d){
      int bo = (d * 128 + lane * 2) ^ ((d & 7) << 4);
      sVT[bo >> 1] = val ? e[d] : (unsigned short)0;
    }
  }

  // S^T = K * Q^T
  short8 kf[4], qf[4];
#pragma unroll
  for (int i = 0; i < 4; ++i){
    int px = i * 16 + (lane & 15); if (px > 48) px = 48;
    const unsigned short* base = qkvT + pxaddr(px) * 768 + h * 32 + (lane >> 4) * 8;
    qf[i] = *(const short8*)(base);
    kf[i] = *(const short8*)(base + 256);
  }
  f32x4 s[4][4] = {};
#pragma unroll
  for (int mi = 0; mi < 4; ++mi)
#pragma unroll
    for (int ni = 0; ni < 4; ++ni)
      s[mi][ni] = MFMA16(kf[mi], qf[ni], s[mi][ni]);

  const float cexp = 0.25504437f;   // log2(e)/sqrt(32)
#pragma unroll
  for (int ni = 0; ni < 4; ++ni){
    float m = -3.0e38f;
#pragma unroll
    for (int mi = 0; mi < 4; ++mi)
#pragma unroll
      for (int r = 0; r < 4; ++r){
        int kp = mi * 16 + ((lane >> 4) * 4) + r;
        if (kp < 49) m = fmaxf(m, s[mi][ni][r]);
      }
    m = fmaxf(m, __shfl_xor(m, 16));
    m = fmaxf(m, __shfl_xor(m, 32));
    float sum = 0.f;
    float pv[4][4];
#pragma unroll
    for (int mi = 0; mi < 4; ++mi)
#pragma unroll
      for (int r = 0; r < 4; ++r){
        int kp = mi * 16 + ((lane >> 4) * 4) + r;
        float e2 = (kp < 49) ? exp2f((s[mi][ni][r] - m) * cexp) : 0.f;
        pv[mi][r] = e2; sum += e2;
      }
    sum += __shfl_xor(sum, 16);
    sum += __shfl_xor(sum, 32);
    float inv = 1.0f / sum;
    int q = ni * 16 + (lane & 15);
#pragma unroll
    for (int mi = 0; mi < 4; ++mi)
#pragma unroll
      for (int r = 0; r < 4; ++r){
        int kp = mi * 16 + ((lane >> 4) * 4) + r;
        int bo = (q * 128 + kp * 2) ^ ((q & 7) << 4);
        sP[bo >> 1] = f2bf(pv[mi][r] * inv);
      }
  }

  // O = P * V
  f32x4 o[4][2] = {};
#pragma unroll
  for (int kc = 0; kc < 2; ++kc){
    short8 pa[4], vb[2];
#pragma unroll
    for (int mtp = 0; mtp < 4; ++mtp){
      int row = mtp * 16 + (lane & 15);
      int bo = (row * 128 + kc * 64 + (lane >> 4) * 16) ^ ((row & 7) << 4);
      pa[mtp] = *(const short8*)(sP + (bo >> 1));
    }
#pragma unroll
    for (int ntp = 0; ntp < 2; ++ntp){
      int row = ntp * 16 + (lane & 15);
      int bo = (row * 128 + kc * 64 + (lane >> 4) * 16) ^ ((row & 7) << 4);
      vb[ntp] = *(const short8*)(sVT + (bo >> 1));
    }
#pragma unroll
    for (int mtp = 0; mtp < 4; ++mtp)
#pragma unroll
      for (int ntp = 0; ntp < 2; ++ntp)
        o[mtp][ntp] = MFMA16(pa[mtp], vb[ntp], o[mtp][ntp]);
  }

  // restage O through LDS -> 16B panel stores (196 chunks instead of 1568 u16)
  unsigned short* sO = sP;   // P dead; 64px * 32ch
#pragma unroll
  for (int mtp = 0; mtp < 4; ++mtp)
#pragma unroll
    for (int r = 0; r < 4; ++r){
      int q = mtp * 16 + (lane >> 4) * 4 + r;
      sO[q * 32 + (lane & 15)]      = f2bf(o[mtp][0][r]);
      sO[q * 32 + (lane & 15) + 16] = f2bf(o[mtp][1][r]);
    }
  __syncthreads();
  size_t pb0 = (size_t)b * 392 * 4;
#pragma unroll
  for (int it = 0; it < 4; ++it){
    int id = it * 64 + lane;
    if (id < 196){
      int px = id >> 2, ck = id & 3;
      short8 v = *(const short8*)(sO + px * 32 + ck * 8);
      int pg = (wh * 7 + px / 7) * 224 + ww * 7 + px % 7;
      int nt = pg >> 7, pr = pg & 127;
      int c64 = ((h & 1) << 5) + ck * 8;
      size_t off = ((pb0 + (size_t)nt * 4 + (h >> 1))) * 8192 + panel_off(pr, c64);
      *(short8*)(attnP + off) = v;
    }
  }
}

// ---------------- GEMM out + residual + per-block BN partials (no atomics) ----------------
__global__ __launch_bounds__(256) void k_gemm_out(const unsigned short* __restrict__ Wp,
                                                  const unsigned short* __restrict__ Bp,
                                                  const float* __restrict__ x,
                                                  float* __restrict__ y,
                                                  float* __restrict__ partials){
  int bid = blockIdx.x;
  int wg = (bid & 7) * 392 + (bid >> 3);     // 3136 = 8*392
  int mt = wg & 1; int rest = wg >> 1;       // mt fastest
  int nt = rest % 392; int b = rest / 392;

  __shared__ __align__(16) unsigned short lds[32768];  // dbuf

  int tid = threadIdx.x;
  int lane = tid & 63;
  int wave = tid >> 6;
  int wm = wave >> 1, wn = wave & 1;

  const unsigned short* Apan = Wp + (size_t)mt * 4 * 8192;
  const unsigned short* Bpan = Bp + ((size_t)(b * 392 + nt)) * 4 * 8192;

  int aoff[2][4], boff[2][4];
#pragma unroll
  for (int kk = 0; kk < 2; ++kk)
#pragma unroll
    for (int i = 0; i < 4; ++i){
      int rowA = wm * 64 + i * 16 + (lane & 15);
      aoff[kk][i] = rowA * 64 + (((kk * 4 + (lane >> 4)) ^ (rowA & 7)) << 3);
      int rowB = wn * 64 + i * 16 + (lane & 15);
      boff[kk][i] = rowB * 64 + (((kk * 4 + (lane >> 4)) ^ (rowB & 7)) << 3);
    }
  int cb = wave * 2048;
  f32x4 acc[4][4] = {};

#pragma unroll
  for (int j = 0; j < 4; ++j){
    int o2 = cb + j * 512;
    GLL16(Apan + o2 + lane * 8, lds + o2);
    GLL16(Bpan + o2 + lane * 8, lds + 8192 + o2);
  }
  __syncthreads();

  int cur = 0;
  for (int kq = 0; kq < 4; ++kq){
    if (kq < 3){
      const unsigned short* Ak = Apan + (kq + 1) * 8192;
      const unsigned short* Bk = Bpan + (kq + 1) * 8192;
      unsigned short* dst = lds + (cur ^ 1) * 16384;
#pragma unroll
      for (int j = 0; j < 4; ++j){
        int o2 = cb + j * 512;
        GLL16(Ak + o2 + lane * 8, dst + o2);
        GLL16(Bk + o2 + lane * 8, dst + 8192 + o2);
      }
    }
    const unsigned short* Alds = lds + cur * 16384;
    const unsigned short* Blds = Alds + 8192;
#pragma unroll
    for (int kk = 0; kk < 2; ++kk){
      short8 af[4], bfv[4];
#pragma unroll
      for (int i = 0; i < 4; ++i) af[i]  = *(const short8*)(Alds + aoff[kk][i]);
#pragma unroll
      for (int j = 0; j < 4; ++j) bfv[j] = *(const short8*)(Blds + boff[kk][j]);
#pragma unroll
      for (int i = 0; i < 4; ++i)
#pragma unroll
        for (int j = 0; j < 4; ++j)
          acc[i][j] = MFMA16(af[i], bfv[j], acc[i][j]);
    }
    __syncthreads();
    cur ^= 1;
  }
  // epilogue: residual add, fp32 store, per-channel partial sums
  float ps[4][4] = {}, pq[4][4] = {};
#pragma unroll
  for (int i = 0; i < 4; ++i)
#pragma unroll
    for (int j = 0; j < 4; ++j){
      int o = mt * 128 + wm * 64 + i * 16 + (lane >> 4) * 4;
      int p = nt * 128 + wn * 64 + j * 16 + (lane & 15);
      size_t base = ((size_t)(b * 256 + o)) * HW_ + p;
#pragma unroll
      for (int r2 = 0; r2 < 4; ++r2){
        float v = acc[i][j][r2] + x[base + (size_t)r2 * HW_];
        y[base + (size_t)r2 * HW_] = v;
        ps[i][r2] += v;
        pq[i][r2] += v * v;
      }
    }
  float* fl = (float*)lds;    // [wn 2][cl 128] sums, +256 sq
#pragma unroll
  for (int i = 0; i < 4; ++i)
#pragma unroll
    for (int r2 = 0; r2 < 4; ++r2){
      float a = ps[i][r2], q2 = pq[i][r2];
      a += __shfl_xor(a, 1);  q2 += __shfl_xor(q2, 1);
      a += __shfl_xor(a, 2);  q2 += __shfl_xor(q2, 2);
      a += __shfl_xor(a, 4);  q2 += __shfl_xor(q2, 4);
      a += __shfl_xor(a, 8);  q2 += __shfl_xor(q2, 8);
      if ((lane & 15) == 0){
        int cl = wm * 64 + i * 16 + (lane >> 4) * 4 + r2;
        fl[wn * 128 + cl] = a;
        fl[256 + wn * 128 + cl] = q2;
      }
    }
  __syncthreads();
  if (tid < 128){
    partials[(size_t)wg * 256 + tid]       = fl[tid] + fl[128 + tid];
    partials[(size_t)wg * 256 + 128 + tid] = fl[256 + tid] + fl[384 + tid];
  }
}

// ---------------- reduce per-block partials -> mean / rsqrt ----------------
__global__ __launch_bounds__(256) void k_stats2(const float* __restrict__ partials, float* __restrict__ stats){
  int c = blockIdx.x;           // 0..255
  int mt = c >> 7, cl = c & 127;
  int t = threadIdx.x;
  float s = 0.f, q = 0.f;
  for (int idx = t; idx < 1568; idx += 256){
    const float* p = partials + (size_t)(2 * idx + mt) * 256;
    s += p[cl]; q += p[128 + cl];
  }
  __shared__ float r1[256], r2[256];
  r1[t] = s; r2[t] = q; __syncthreads();
  for (int off = 128; off > 0; off >>= 1){
    if (t < off){ r1[t] += r1[t + off]; r2[t] += r2[t + off]; }
    __syncthreads();
  }
  if (t == 0){
    float mean = r1[0] * (1.f / 200704.f);
    float var  = r2[0] * (1.f / 200704.f) - mean * mean;
    stats[c] = mean;
    stats[256 + c] = rsqrtf(var + 1e-5f);
  }
}

// ---------------- in-place normalize ----------------
__global__ __launch_bounds__(256) void k_norm(float* __restrict__ y, const float* __restrict__ stats,
                                              const float* __restrict__ gamma, const float* __restrict__ beta){
  const long long total = 12845056LL;  // 51380224 / 4
  for (long long idx = (long long)blockIdx.x * 256 + threadIdx.x; idx < total; idx += (long long)gridDim.x * 256){
    int c = (int)((idx / 12544) & 255);
    float sc = stats[256 + c] * gamma[c];
    float sh = beta[c] - stats[c] * sc;
    float4* p = (float4*)y + idx;
    float4 v = *p;
    v.x = v.x * sc + sh; v.y = v.y * sc + sh; v.z = v.z * sc + sh; v.w = v.w * sc + sh;
    *p = v;
  }
}

extern "C" void kernel_launch(void* const* d_in, const int* in_sizes, int n_in,
                              void* d_out, int out_size, void* d_ws, size_t ws_size,
                              hipStream_t stream){
  const float* x     = (const float*)d_in[0];
  const float* Wq    = (const float*)d_in[1];
  const float* Wk    = (const float*)d_in[2];
  const float* Wv    = (const float*)d_in[3];
  const float* Wo    = (const float*)d_in[4];
  const float* gamma = (const float*)d_in[5];
  const float* beta  = (const float*)d_in[6];
  float* out = (float*)d_out;

  char* ws = (char*)d_ws;
  unsigned short* Wqkv_b = (unsigned short*)ws;                               // 393216 B
  unsigned short* Wo_b   = (unsigned short*)(ws + 393216);                    // 131072 B
  float*          stats  = (float*)(ws + 524288);                             // 2048 B
  unsigned short* xbT    = (unsigned short*)(ws + 1048576);                   // 102760448 B (B-panels)
  unsigned short* qkvT   = (unsigned short*)(ws + 1048576 + 102760448);       // 308281344 B
  float*          partials = (float*)(ws + 1048576 + 102760448 + 308281344);  // 3211264 B
  unsigned short* attnP  = xbT;  // alias: xbT dead after k_gemm_qkv (stream-ordered)

  k_convw<<<128, 256, 0, stream>>>(Wq, Wk, Wv, Wo, Wqkv_b, Wo_b);
  k_xpose<<<4 * 4 * 784, 256, 0, stream>>>(x, xbT);
  k_gemm_qkv<<<9408, 256, 0, stream>>>(Wqkv_b, xbT, qkvT);
  k_attn<<<32768, 64, 0, stream>>>(qkvT, attnP);
  k_gemm_out<<<3136, 256, 0, stream>>>(Wo_b, attnP, x, out, partials);
  k_stats2<<<256, 256, 0, stream>>>(partials, stats);
  k_norm<<<4096, 256, 0, stream>>>(out, stats, gamma, beta);
}

// Round 5
// 495.904 us; speedup vs baseline: 1.5069x; 1.1110x over previous
//
#include <hip/hip_runtime.h>
#include <stdint.h>

typedef __attribute__((ext_vector_type(8))) short short8;
typedef __attribute__((ext_vector_type(4))) float f32x4;

#define MFMA16(a,b,c) __builtin_amdgcn_mfma_f32_16x16x32_bf16((a),(b),(c),0,0,0)

// async global->LDS DMA, 16B per lane; LDS dest = wave-uniform base + lane*16B
#define GLL16(g, l) __builtin_amdgcn_global_load_lds( \
    (const __attribute__((address_space(1))) void*)(g), \
    (__attribute__((address_space(3))) void*)(l), 16, 0, 0)

__device__ __forceinline__ unsigned short f2bf(float f){
  unsigned u = __builtin_bit_cast(unsigned, f);
  u += 0x7fffu + ((u >> 16) & 1u);
  return (unsigned short)(u >> 16);
}

static constexpr int HW_ = 50176;   // 224*224

// offset of element (row r 0..127, k c64 0..63) inside one 8192-elem panel,
// XOR-swizzled so ds_read_b128 of a 16-lane column slice is conflict-free
__device__ __forceinline__ int panel_off(int r, int c64){
  return r * 64 + ((((c64 >> 3) ^ (r & 7))) << 3) + (c64 & 7);
}

// ---------------- weights fp32 -> bf16 ----------------
// Wf: qkv B-fragment stream: chunk gid = ((h*8+kq)*6+t)*64+lane holds
//     W{q,k,v}[h*32+(t&1)*16+(lane&15)][kq*32+(lane>>4)*8 .. +8)
// Wob: out-proj panels (round-4 layout, for k_gemm_out)
__global__ __launch_bounds__(256) void k_convw(const float* __restrict__ Wq, const float* __restrict__ Wk,
                        const float* __restrict__ Wv, const float* __restrict__ Wo,
                        unsigned short* __restrict__ Wf, unsigned short* __restrict__ Wob){
  int gid = blockIdx.x * 256 + threadIdx.x;   // grid 128 -> 32768
  if (gid < 24576){
    int lane = gid & 63;
    int r1 = gid >> 6;          // 0..383
    int t = r1 % 6;
    int r2 = r1 / 6;            // 0..63
    int kq = r2 & 7, hh = r2 >> 3;
    const float* W = (t < 2) ? Wq : (t < 4) ? Wk : Wv;
    int ch = hh * 32 + (t & 1) * 16 + (lane & 15);
    int k0 = kq * 32 + (lane >> 4) * 8;
    const float* src = W + ch * 256 + k0;
    float4 a = *(const float4*)src, b2 = *(const float4*)(src + 4);
    short8 v;
    v[0]=f2bf(a.x); v[1]=f2bf(a.y); v[2]=f2bf(a.z); v[3]=f2bf(a.w);
    v[4]=f2bf(b2.x); v[5]=f2bf(b2.y); v[6]=f2bf(b2.z); v[7]=f2bf(b2.w);
    *(short8*)(Wf + (size_t)gid * 8) = v;
  } else {
    int og = gid - 24576;       // 0..8191
    int o = og >> 5, ck = og & 31;
    const float* src = Wo + o * 256 + ck * 8;
    float4 a = *(const float4*)src, b2 = *(const float4*)(src + 4);
    short8 v;
    v[0]=f2bf(a.x); v[1]=f2bf(a.y); v[2]=f2bf(a.z); v[3]=f2bf(a.w);
    v[4]=f2bf(b2.x); v[5]=f2bf(b2.y); v[6]=f2bf(b2.z); v[7]=f2bf(b2.w);
    int kq = ck >> 3;
    int off = panel_off(o & 127, (ck & 7) * 8);
    *(short8*)(Wob + ((o >> 7) * 4 + kq) * 8192 + off) = v;
  }
}

// ---------------- fused: x-gather + qkv GEMM + window attention ----------------
// block = 1 window (49 px pad 64), 8 waves = 8 heads, 128 KB LDS
// LDS elems (u16): [0..16384) q[64px][256c swz]; [16384..32768) k (same)
//                  attn phase: sP wave h at h*4096 (P[64q][64k'] swz)
// [32768..49152) vT[256ch][64px swz granules]
// [49152..65536) phase1: x[64px][256c swz]; phase3: O[64px][256c swz]
__global__ __launch_bounds__(512) void k_fused(const float* __restrict__ x,
                                               const unsigned short* __restrict__ Wf,
                                               unsigned short* __restrict__ attnP){
  int bid = blockIdx.x;
  int wg = (bid & 7) * 512 + (bid >> 3);    // 4096 = 8*512, ww-contiguous per XCD
  int b = wg >> 10;
  int win = wg & 1023;
  int wh = win >> 5, ww = win & 31;
  int tid = threadIdx.x;
  int lane = tid & 63;
  int h = tid >> 6;                          // wave = head

  __shared__ __align__(16) unsigned short lds[65536];   // 128 KB

  // ---- phase 0: gather x window (f32 -> bf16) into region C ----
  {
    int px = tid & 63, cq = tid >> 6;
    if (px < 49){
      int r = px / 7, cl = px % 7;
      const float* gsrc = x + (size_t)b * 256 * HW_ + (size_t)(wh * 7 + r) * 224 + ww * 7 + cl;
#pragma unroll
      for (int c2 = 0; c2 < 32; ++c2){
        int c = cq * 32 + c2;
        float v = gsrc[(size_t)c * HW_];
        lds[49152 + px * 256 + (((c >> 3) ^ (px & 7)) << 3) + (c & 7)] = f2bf(v);
      }
    } else {
#pragma unroll
      for (int c2 = 0; c2 < 32; ++c2){
        int c = cq * 32 + c2;
        lds[49152 + px * 256 + (((c >> 3) ^ (px & 7)) << 3) + (c & 7)] = 0;
      }
    }
  }
  __syncthreads();

  // ---- phase 1: qkv GEMM; W streamed from L2 as B-frags, x from LDS ----
  f32x4 aq[4][2] = {}, ak[4][2] = {}, av[2][4] = {};
  for (int kq = 0; kq < 8; ++kq){
    short8 xf[4];
#pragma unroll
    for (int pt = 0; pt < 4; ++pt){
      int px = pt * 16 + (lane & 15);
      int chk = (kq * 4 + (lane >> 4)) ^ (px & 7);
      xf[pt] = *(const short8*)(lds + 49152 + px * 256 + chk * 8);
    }
    short8 wfr[6];
#pragma unroll
    for (int t = 0; t < 6; ++t)
      wfr[t] = *(const short8*)(Wf + ((size_t)((h * 8 + kq) * 6 + t) * 64 + lane) * 8);
#pragma unroll
    for (int pt = 0; pt < 4; ++pt){
      aq[pt][0] = MFMA16(xf[pt], wfr[0], aq[pt][0]);   // D[px][ch]
      aq[pt][1] = MFMA16(xf[pt], wfr[1], aq[pt][1]);
      ak[pt][0] = MFMA16(xf[pt], wfr[2], ak[pt][0]);
      ak[pt][1] = MFMA16(xf[pt], wfr[3], ak[pt][1]);
      av[0][pt] = MFMA16(wfr[4], xf[pt], av[0][pt]);   // D[ch][px] (transposed v)
      av[1][pt] = MFMA16(wfr[5], xf[pt], av[1][pt]);
    }
  }
  // write q,k -> region A   (D[px][ch]: lane col ch=lane&15, rows px=(lane>>4)*4+j)
#pragma unroll
  for (int pt = 0; pt < 4; ++pt)
#pragma unroll
    for (int t = 0; t < 2; ++t)
#pragma unroll
      for (int j = 0; j < 4; ++j){
        int px = pt * 16 + (lane >> 4) * 4 + j;
        int ch = h * 32 + t * 16 + (lane & 15);
        int pos = px * 256 + (((ch >> 3) ^ (px & 7)) << 3) + (ch & 7);
        lds[pos]         = f2bf(aq[pt][t][j]);
        lds[16384 + pos] = f2bf(ak[pt][t][j]);
      }
  // write vT -> region B   (D[ch][px]: lane col px=lane&15, rows ch=(lane>>4)*4+j)
#pragma unroll
  for (int ct = 0; ct < 2; ++ct)
#pragma unroll
    for (int pt = 0; pt < 4; ++pt)
#pragma unroll
      for (int j = 0; j < 4; ++j){
        int ch = h * 32 + ct * 16 + (lane >> 4) * 4 + j;
        int px = pt * 16 + (lane & 15);
        lds[32768 + ch * 64 + (((px >> 3) ^ (ch & 7)) << 3) + (px & 7)] = f2bf(av[ct][pt][j]);
      }
  __syncthreads();

  // ---- phase 2: S^T = K * Q^T ----
  short8 kf[4], qf[4];
#pragma unroll
  for (int i = 0; i < 4; ++i){
    int px = i * 16 + (lane & 15);
    int chk = (h * 4 + (lane >> 4)) ^ (px & 7);
    qf[i] = *(const short8*)(lds + px * 256 + chk * 8);
    kf[i] = *(const short8*)(lds + 16384 + px * 256 + chk * 8);
  }
  f32x4 s[4][4] = {};
#pragma unroll
  for (int mi = 0; mi < 4; ++mi)
#pragma unroll
    for (int ni = 0; ni < 4; ++ni)
      s[mi][ni] = MFMA16(kf[mi], qf[ni], s[mi][ni]);
  __syncthreads();                 // all q/k reads done; region A becomes sP

  // ---- softmax over k' per q column; write P bf16 to sP (wave-private 8 KB) ----
  const float cexp = 0.25504437f;  // log2(e)/sqrt(32)
  unsigned short* sP = lds + h * 4096;
#pragma unroll
  for (int ni = 0; ni < 4; ++ni){
    float m = -3.0e38f;
#pragma unroll
    for (int mi = 0; mi < 4; ++mi)
#pragma unroll
      for (int r = 0; r < 4; ++r){
        int kp = mi * 16 + ((lane >> 4) * 4) + r;
        if (kp < 49) m = fmaxf(m, s[mi][ni][r]);
      }
    m = fmaxf(m, __shfl_xor(m, 16));
    m = fmaxf(m, __shfl_xor(m, 32));
    float sum = 0.f;
    float pv[4][4];
#pragma unroll
    for (int mi = 0; mi < 4; ++mi)
#pragma unroll
      for (int r = 0; r < 4; ++r){
        int kp = mi * 16 + ((lane >> 4) * 4) + r;
        float e2 = (kp < 49) ? exp2f((s[mi][ni][r] - m) * cexp) : 0.f;
        pv[mi][r] = e2; sum += e2;
      }
    sum += __shfl_xor(sum, 16);
    sum += __shfl_xor(sum, 32);
    float inv = 1.0f / sum;
    int q = ni * 16 + (lane & 15);
#pragma unroll
    for (int mi = 0; mi < 4; ++mi)
#pragma unroll
      for (int r = 0; r < 4; ++r){
        int kp = mi * 16 + ((lane >> 4) * 4) + r;
        int bo = (q * 128 + kp * 2) ^ ((q & 7) << 4);
        sP[bo >> 1] = f2bf(pv[mi][r] * inv);
      }
  }

  // ---- phase 3: O = P * V ----
  f32x4 o[4][2] = {};
#pragma unroll
  for (int kc = 0; kc < 2; ++kc){
    short8 pa[4], vb[2];
#pragma unroll
    for (int mtp = 0; mtp < 4; ++mtp){
      int row = mtp * 16 + (lane & 15);
      int bo = (row * 128 + kc * 64 + (lane >> 4) * 16) ^ ((row & 7) << 4);
      pa[mtp] = *(const short8*)(sP + (bo >> 1));
    }
#pragma unroll
    for (int ntp = 0; ntp < 2; ++ntp){
      int ch = h * 32 + ntp * 16 + (lane & 15);
      int k0 = kc * 32 + (lane >> 4) * 8;
      vb[ntp] = *(const short8*)(lds + 32768 + ch * 64 + (((k0 >> 3) ^ (ch & 7)) << 3));
    }
#pragma unroll
    for (int mtp = 0; mtp < 4; ++mtp)
#pragma unroll
      for (int ntp = 0; ntp < 2; ++ntp)
        o[mtp][ntp] = MFMA16(pa[mtp], vb[ntp], o[mtp][ntp]);
  }
  // O -> region C (x dead since phase-1 barrier)
#pragma unroll
  for (int mtp = 0; mtp < 4; ++mtp)
#pragma unroll
    for (int ntp = 0; ntp < 2; ++ntp)
#pragma unroll
      for (int r = 0; r < 4; ++r){
        int px = mtp * 16 + (lane >> 4) * 4 + r;
        int ch = h * 32 + ntp * 16 + (lane & 15);
        lds[49152 + px * 256 + (((ch >> 3) ^ (px & 7)) << 3) + (ch & 7)] = f2bf(o[mtp][ntp][r]);
      }
  __syncthreads();

  // ---- phase 4: cooperative 16B panel stores ----
  size_t pb0 = (size_t)b * 392 * 4;
#pragma unroll
  for (int it = 0; it < 4; ++it){
    int id = it * 512 + tid;                 // 0..2047 = 64 px * 32 chunks
    int px = id >> 5, ck = id & 31;
    if (px < 49){
      short8 v = *(const short8*)(lds + 49152 + px * 256 + ((ck ^ (px & 7)) << 3));
      int pg = (wh * 7 + px / 7) * 224 + ww * 7 + px % 7;
      int nt = pg >> 7, pr = pg & 127;
      size_t off = (pb0 + (size_t)nt * 4 + (ck >> 3)) * 8192 + panel_off(pr, (ck & 7) * 8);
      *(short8*)(attnP + off) = v;
    }
  }
}

// ---------------- GEMM out + residual + per-block BN partials (no atomics) ----------------
__global__ __launch_bounds__(256) void k_gemm_out(const unsigned short* __restrict__ Wp,
                                                  const unsigned short* __restrict__ Bp,
                                                  const float* __restrict__ x,
                                                  float* __restrict__ y,
                                                  float* __restrict__ partials){
  int bid = blockIdx.x;
  int wg = (bid & 7) * 392 + (bid >> 3);     // 3136 = 8*392
  int mt = wg & 1; int rest = wg >> 1;       // mt fastest
  int nt = rest % 392; int b = rest / 392;

  __shared__ __align__(16) unsigned short lds[32768];  // dbuf

  int tid = threadIdx.x;
  int lane = tid & 63;
  int wave = tid >> 6;
  int wm = wave >> 1, wn = wave & 1;

  const unsigned short* Apan = Wp + (size_t)mt * 4 * 8192;
  const unsigned short* Bpan = Bp + ((size_t)(b * 392 + nt)) * 4 * 8192;

  int aoff[2][4], boff[2][4];
#pragma unroll
  for (int kk = 0; kk < 2; ++kk)
#pragma unroll
    for (int i = 0; i < 4; ++i){
      int rowA = wm * 64 + i * 16 + (lane & 15);
      aoff[kk][i] = rowA * 64 + (((kk * 4 + (lane >> 4)) ^ (rowA & 7)) << 3);
      int rowB = wn * 64 + i * 16 + (lane & 15);
      boff[kk][i] = rowB * 64 + (((kk * 4 + (lane >> 4)) ^ (rowB & 7)) << 3);
    }
  int cb = wave * 2048;
  f32x4 acc[4][4] = {};

#pragma unroll
  for (int j = 0; j < 4; ++j){
    int o2 = cb + j * 512;
    GLL16(Apan + o2 + lane * 8, lds + o2);
    GLL16(Bpan + o2 + lane * 8, lds + 8192 + o2);
  }
  __syncthreads();

  int cur = 0;
  for (int kq = 0; kq < 4; ++kq){
    if (kq < 3){
      const unsigned short* Ak = Apan + (kq + 1) * 8192;
      const unsigned short* Bk = Bpan + (kq + 1) * 8192;
      unsigned short* dst = lds + (cur ^ 1) * 16384;
#pragma unroll
      for (int j = 0; j < 4; ++j){
        int o2 = cb + j * 512;
        GLL16(Ak + o2 + lane * 8, dst + o2);
        GLL16(Bk + o2 + lane * 8, dst + 8192 + o2);
      }
    }
    const unsigned short* Alds = lds + cur * 16384;
    const unsigned short* Blds = Alds + 8192;
#pragma unroll
    for (int kk = 0; kk < 2; ++kk){
      short8 af[4], bfv[4];
#pragma unroll
      for (int i = 0; i < 4; ++i) af[i]  = *(const short8*)(Alds + aoff[kk][i]);
#pragma unroll
      for (int j = 0; j < 4; ++j) bfv[j] = *(const short8*)(Blds + boff[kk][j]);
#pragma unroll
      for (int i = 0; i < 4; ++i)
#pragma unroll
        for (int j = 0; j < 4; ++j)
          acc[i][j] = MFMA16(af[i], bfv[j], acc[i][j]);
    }
    __syncthreads();
    cur ^= 1;
  }
  // epilogue: residual add, fp32 store, per-channel partial sums
  float ps[4][4] = {}, pq[4][4] = {};
#pragma unroll
  for (int i = 0; i < 4; ++i)
#pragma unroll
    for (int j = 0; j < 4; ++j){
      int o = mt * 128 + wm * 64 + i * 16 + (lane >> 4) * 4;
      int p = nt * 128 + wn * 64 + j * 16 + (lane & 15);
      size_t base = ((size_t)(b * 256 + o)) * HW_ + p;
#pragma unroll
      for (int r2 = 0; r2 < 4; ++r2){
        float v = acc[i][j][r2] + x[base + (size_t)r2 * HW_];
        y[base + (size_t)r2 * HW_] = v;
        ps[i][r2] += v;
        pq[i][r2] += v * v;
      }
    }
  float* fl = (float*)lds;    // [wn 2][cl 128] sums, +256 sq
#pragma unroll
  for (int i = 0; i < 4; ++i)
#pragma unroll
    for (int r2 = 0; r2 < 4; ++r2){
      float a = ps[i][r2], q2 = pq[i][r2];
      a += __shfl_xor(a, 1);  q2 += __shfl_xor(q2, 1);
      a += __shfl_xor(a, 2);  q2 += __shfl_xor(q2, 2);
      a += __shfl_xor(a, 4);  q2 += __shfl_xor(q2, 4);
      a += __shfl_xor(a, 8);  q2 += __shfl_xor(q2, 8);
      if ((lane & 15) == 0){
        int cl = wm * 64 + i * 16 + (lane >> 4) * 4 + r2;
        fl[wn * 128 + cl] = a;
        fl[256 + wn * 128 + cl] = q2;
      }
    }
  __syncthreads();
  if (tid < 128){
    partials[(size_t)wg * 256 + tid]       = fl[tid] + fl[128 + tid];
    partials[(size_t)wg * 256 + 128 + tid] = fl[256 + tid] + fl[384 + tid];
  }
}

// ---------------- reduce per-block partials -> mean / rsqrt ----------------
__global__ __launch_bounds__(256) void k_stats2(const float* __restrict__ partials, float* __restrict__ stats){
  int c = blockIdx.x;           // 0..255
  int mt = c >> 7, cl = c & 127;
  int t = threadIdx.x;
  float s = 0.f, q = 0.f;
  for (int idx = t; idx < 1568; idx += 256){
    const float* p = partials + (size_t)(2 * idx + mt) * 256;
    s += p[cl]; q += p[128 + cl];
  }
  __shared__ float r1[256], r2[256];
  r1[t] = s; r2[t] = q; __syncthreads();
  for (int off = 128; off > 0; off >>= 1){
    if (t < off){ r1[t] += r1[t + off]; r2[t] += r2[t + off]; }
    __syncthreads();
  }
  if (t == 0){
    float mean = r1[0] * (1.f / 200704.f);
    float var  = r2[0] * (1.f / 200704.f) - mean * mean;
    stats[c] = mean;
    stats[256 + c] = rsqrtf(var + 1e-5f);
  }
}

// ---------------- in-place normalize ----------------
__global__ __launch_bounds__(256) void k_norm(float* __restrict__ y, const float* __restrict__ stats,
                                              const float* __restrict__ gamma, const float* __restrict__ beta){
  const long long total = 12845056LL;  // 51380224 / 4
  for (long long idx = (long long)blockIdx.x * 256 + threadIdx.x; idx < total; idx += (long long)gridDim.x * 256){
    int c = (int)((idx / 12544) & 255);
    float sc = stats[256 + c] * gamma[c];
    float sh = beta[c] - stats[c] * sc;
    float4* p = (float4*)y + idx;
    float4 v = *p;
    v.x = v.x * sc + sh; v.y = v.y * sc + sh; v.z = v.z * sc + sh; v.w = v.w * sc + sh;
    *p = v;
  }
}

extern "C" void kernel_launch(void* const* d_in, const int* in_sizes, int n_in,
                              void* d_out, int out_size, void* d_ws, size_t ws_size,
                              hipStream_t stream){
  const float* x     = (const float*)d_in[0];
  const float* Wq    = (const float*)d_in[1];
  const float* Wk    = (const float*)d_in[2];
  const float* Wv    = (const float*)d_in[3];
  const float* Wo    = (const float*)d_in[4];
  const float* gamma = (const float*)d_in[5];
  const float* beta  = (const float*)d_in[6];
  float* out = (float*)d_out;

  char* ws = (char*)d_ws;
  unsigned short* Wf     = (unsigned short*)ws;                               // 393216 B (qkv frag stream)
  unsigned short* Wo_b   = (unsigned short*)(ws + 393216);                    // 131072 B
  float*          stats  = (float*)(ws + 524288);                             // 2048 B
  unsigned short* attnP  = (unsigned short*)(ws + 1048576);                   // 102760448 B (B-panels)
  float*          partials = (float*)(ws + 1048576 + 102760448);              // 3211264 B

  k_convw<<<128, 256, 0, stream>>>(Wq, Wk, Wv, Wo, Wf, Wo_b);
  k_fused<<<4096, 512, 0, stream>>>(x, Wf, attnP);
  k_gemm_out<<<3136, 256, 0, stream>>>(Wo_b, attnP, x, out, partials);
  k_stats2<<<256, 256, 0, stream>>>(partials, stats);
  k_norm<<<4096, 256, 0, stream>>>(out, stats, gamma, beta);
}